// Round 2
// baseline (119.779 us; speedup 1.0000x reference)
//
#include <hip/hip_runtime.h>

// Decimate-by-4 with 129-tap windowed-sinc (polyphase direct form).
// y[r,m] = sum_{j=0..128} k[j] * x_ext[r, 4m + j - 64]
//   x_ext: reflect on left (x_ext[-t] = x[t]), zero past T.
// Polyphase: j = 4a+p -> y[m] = sum_p sum_a k[4a+p] * u_p[m+a],
//   u_p[t] = x_ext[4t + p - 64]  (stride-1 FIR per phase).

#define T_LEN 1048576
#define OUT_PER_ROW (T_LEN / 4)              // 262144
#define NTAPS 129
#define C 8                                   // outputs per thread
#define BLOCK 256
#define OUT_PER_BLOCK (BLOCK * C)             // 2048
#define BLOCKS_PER_ROW (OUT_PER_ROW / OUT_PER_BLOCK)  // 128
#define NSTAGE (OUT_PER_BLOCK + 32)           // 2080 u-values per phase
#define UPAD 2344                             // padidx(2079)=2338, rounded up

__device__ __forceinline__ int padidx(int i) { return i + (i >> 3); }

__global__ __launch_bounds__(BLOCK) void decim_kernel(
    const float* __restrict__ x, const float* __restrict__ k,
    float* __restrict__ out) {
  // 4 phase-separated staging arrays; pad every 8th element so that
  // compute reads (lane stride 8 floats) become stride 9 -> gcd(9,32)=1
  // -> 2 lanes/bank across wave64 = conflict-free (m136).
  __shared__ float s_u[4][UPAD];
  __shared__ float s_k[132];

  const int tid = threadIdx.x;
  const int bx  = blockIdx.x;
  const int row = bx >> 7;                    // / BLOCKS_PER_ROW
  const int blk = bx & (BLOCKS_PER_ROW - 1);
  const int M0  = blk * OUT_PER_BLOCK;
  const float* xr = x + (size_t)row * T_LEN;

  if (tid < 132) s_k[tid] = (tid < NTAPS) ? k[tid] : 0.0f;

  const int gbase = 4 * M0 - 64;              // first x index needed
  if (gbase >= 0 && gbase + 4 * NSTAGE <= T_LEN) {
    // interior fast path: coalesced float4 loads, de-interleave to phases
    const float4* src = (const float4*)(xr + gbase);
    for (int i = tid; i < NSTAGE; i += BLOCK) {
      float4 v = src[i];
      int a = padidx(i);
      s_u[0][a] = v.x; s_u[1][a] = v.y; s_u[2][a] = v.z; s_u[3][a] = v.w;
    }
  } else {
    // edge blocks (first/last of each row): reflect left, zero right
    for (int i = tid; i < NSTAGE; i += BLOCK) {
      int a = padidx(i);
      int g0 = gbase + 4 * i;
      #pragma unroll
      for (int p = 0; p < 4; ++p) {
        int g = g0 + p;
        float v = 0.0f;
        if (g < 0) v = xr[-g];
        else if (g < T_LEN) v = xr[g];
        s_u[p][a] = v;
      }
    }
  }
  __syncthreads();

  const int m0 = tid * C;
  float acc[C];
  #pragma unroll
  for (int i = 0; i < C; ++i) acc[i] = 0.0f;

  // 32 taps per phase (tap j=128 i.e. p=0,a=32 handled after the loop).
  #pragma unroll 1
  for (int p = 0; p < 4; ++p) {
    float w[C + 31];                          // sliding window, register-resident
    #pragma unroll
    for (int r = 0; r < C + 31; ++r) w[r] = s_u[p][padidx(m0 + r)];
    float kp[32];
    #pragma unroll
    for (int a = 0; a < 32; ++a) kp[a] = s_k[4 * a + p];
    #pragma unroll
    for (int i = 0; i < C; ++i) {
      #pragma unroll
      for (int a = 0; a < 32; ++a)
        acc[i] = fmaf(kp[a], w[i + a], acc[i]);
    }
  }
  {
    float k128 = s_k[128];
    #pragma unroll
    for (int i = 0; i < C; ++i)
      acc[i] = fmaf(k128, s_u[0][padidx(m0 + i + 32)], acc[i]);
  }

  float* op = out + (size_t)row * OUT_PER_ROW + M0 + m0;
  *(float4*)(op)     = make_float4(acc[0], acc[1], acc[2], acc[3]);
  *(float4*)(op + 4) = make_float4(acc[4], acc[5], acc[6], acc[7]);
}

extern "C" void kernel_launch(void* const* d_in, const int* in_sizes, int n_in,
                              void* d_out, int out_size, void* d_ws, size_t ws_size,
                              hipStream_t stream) {
  const float* x = (const float*)d_in[0];
  const float* k = (const float*)d_in[1];
  float* out = (float*)d_out;
  const int rows = in_sizes[0] / T_LEN;       // 16
  dim3 grid(rows * BLOCKS_PER_ROW);           // 2048 blocks
  decim_kernel<<<grid, BLOCK, 0, stream>>>(x, k, out);
}

// Round 4
// 110.423 us; speedup vs baseline: 1.0847x; 1.0847x over previous
//
#include <hip/hip_runtime.h>

// Decimate-by-4, 129-tap windowed-sinc.
// y[r,m] = sum_{j=0..128} k[j] * x_ext[r, 4m + j - 64]
//   x_ext: reflect left (x_ext[-t] = x[t]), zero past T (reference zero-pads
//   2000 samples; max touched index 1048639 stays inside that zero region).
//
// Layout: stage the block's x-window (8320 floats = 2080 float4 chunks) in
// LDS. A float4 chunk at position a holds phases p=0..3 of position a, so
// the whole FIR reads 40 ds_read_b128 per thread (affine addresses).
// Bank balance: XOR-swizzle chunks, q ^= (q>>3)&0x70 (involution; lane t at
// step n hits bank-group (n&7)^((t+(n>>3))&7) -> 8 lanes per 4-bank group =
// balanced). LDS dest stays LINEAR for global_load_lds; the SOURCE global
// address is pre-swizzled instead (both-sides rule, m173/m104).
// Taps: uniform loads from global k with compile-time offsets -> s_load.

#define T_LEN 1048576
#define OUT_PER_ROW (T_LEN / 4)                       // 262144
#define C 8                                           // outputs per thread
#define BLOCK 256
#define OUT_PER_BLOCK (BLOCK * C)                     // 2048
#define BLOCKS_PER_ROW (OUT_PER_ROW / OUT_PER_BLOCK)  // 128
#define NCHUNK (OUT_PER_BLOCK + 32)                   // 2080 float4 chunks
#define LDS_BYTES (NCHUNK * 16)                       // 33280

__device__ __forceinline__ unsigned swz(unsigned q) {
  return q ^ ((q >> 3) & 0x70u);                      // XOR byte bits[6:4] ^= bits[9:7]
}

__device__ __forceinline__ void gload_lds16(const void* g, void* l) {
  __builtin_amdgcn_global_load_lds(
      (const __attribute__((address_space(1))) void*)g,
      (__attribute__((address_space(3))) void*)l, 16, 0, 0);
}

__global__ __launch_bounds__(BLOCK, 4) void decim_kernel(
    const float* __restrict__ x, const float* __restrict__ kk,
    float* __restrict__ out) {
  __shared__ __align__(16) char s_mem[LDS_BYTES];

  const int tid = threadIdx.x;
  const int bx  = blockIdx.x;
  const int row = bx >> 7;
  const int blk = bx & (BLOCKS_PER_ROW - 1);
  const int M0  = blk * OUT_PER_BLOCK;
  const float* xr = x + (size_t)row * T_LEN;
  const int win0 = 4 * M0 - 64;                       // window start (abs float idx)

  if (blk != 0 && blk != BLOCKS_PER_ROW - 1) {
    // Interior: async global->LDS, 16B/lane, source pre-swizzled, dest linear.
    const char* gb = (const char*)(xr + win0);
    #pragma unroll
    for (int g = 0; g < 8; ++g) {
      unsigned lq = (unsigned)(g * BLOCK + tid) * 16u;
      gload_lds16(gb + swz(lq), s_mem + lq);
    }
    if (tid < NCHUNK - 8 * BLOCK) {                   // 32 remainder chunks
      unsigned lq = (unsigned)(8 * BLOCK + tid) * 16u;
      gload_lds16(gb + swz(lq), s_mem + lq);
    }
  } else {
    // Edge blocks: reflect left / zero right, write to swizzled LDS address.
    for (int i = tid; i < NCHUNK; i += BLOCK) {
      unsigned lq = (unsigned)i * 16u;
      float v[4];
      #pragma unroll
      for (int p = 0; p < 4; ++p) {
        int g = win0 + 4 * i + p;
        float t = 0.0f;
        if (g < 0) t = xr[-g];
        else if (g < T_LEN) t = xr[g];
        v[p] = t;
      }
      *(float4*)(s_mem + swz(lq)) = make_float4(v[0], v[1], v[2], v[3]);
    }
  }
  __syncthreads();

  const int m0 = tid * C;                             // block-local first output
  float acc[C];
  #pragma unroll
  for (int i = 0; i < C; ++i) acc[i] = 0.0f;

  const unsigned qb = (unsigned)m0 * 16u;
  // Chunk n (thread-local) feeds output c with tap group e = n-c in [0,32]:
  //   j = 4e + p   (e == 32 valid only for p == 0, i.e. k[128]).
  #pragma unroll
  for (int n = 0; n < 40; ++n) {
    unsigned q = qb + (unsigned)n * 16u;
    const float4 w = *(const float4*)(s_mem + swz(q));
    #pragma unroll
    for (int c = 0; c < C; ++c) {
      const int e = n - c;
      if (e < 0 || e > 32) continue;                  // compile-time pruned
      if (e == 32) {
        acc[c] = fmaf(kk[128], w.x, acc[c]);
      } else {
        acc[c] = fmaf(kk[4 * e + 0], w.x, acc[c]);
        acc[c] = fmaf(kk[4 * e + 1], w.y, acc[c]);
        acc[c] = fmaf(kk[4 * e + 2], w.z, acc[c]);
        acc[c] = fmaf(kk[4 * e + 3], w.w, acc[c]);
      }
    }
  }

  float* op = out + (size_t)row * OUT_PER_ROW + M0 + m0;
  *(float4*)(op)     = make_float4(acc[0], acc[1], acc[2], acc[3]);
  *(float4*)(op + 4) = make_float4(acc[4], acc[5], acc[6], acc[7]);
}

extern "C" void kernel_launch(void* const* d_in, const int* in_sizes, int n_in,
                              void* d_out, int out_size, void* d_ws, size_t ws_size,
                              hipStream_t stream) {
  const float* x = (const float*)d_in[0];
  const float* k = (const float*)d_in[1];
  float* out = (float*)d_out;
  const int rows = in_sizes[0] / T_LEN;               // 16
  dim3 grid(rows * BLOCKS_PER_ROW);                   // 2048 blocks
  decim_kernel<<<grid, BLOCK, 0, stream>>>(x, k, out);
}